// Round 11
// baseline (6363.961 us; speedup 1.0000x reference)
//
#include <hip/hip_runtime.h>
#include <math.h>

// Problem constants (fixed by reference)
#define T   1024
#define NB  16
#define HD  512

// ws layout (float offsets)
#define OFF_BAR  0                         // 512 ints: flag[2 dir][4 bgrp][64 uslice]
#define OFF_HH   768                       // h_hist [2][T][NB][HD] = 16,777,216 floats
#define OFF_SH   (OFF_HH + 16777216)       // SH [16384][512] = 8,388,608 floats
#define OFF_SEGP (OFF_SH + 8388608)        // [16384]
#define OFF_GCTX (OFF_SEGP + 16384)        // [16][1024]
#define OFF_SEL  (OFF_GCTX + 16384)        // ints [16][12]

typedef unsigned long long u64;

__device__ __forceinline__ float sigmoidf_(float x){ return 1.0f/(1.0f + __expf(-x)); }
// fast tanh via exp2-based __expf; |err| ~1e-7, graceful saturation at +/-1
__device__ __forceinline__ float tanhf_(float x){ return 1.0f - 2.0f/(1.0f + __expf(2.0f*x)); }

// ---------------------------------------------------------------------------
// Persistent bidirectional LSTM, CHAIN-PAIRED. grid=256 wgs, block=512 (8 waves).
// wg -> (bgrp = wg&3 : 4 batches, uslice = wg>>2 : 8 hidden units). Each wg
// serves BOTH directions (chain A = fwd, chain B = bwd) for its units:
// per iteration it advances A one step, then B one step. The cross-CU
// store->flag->poll latency of chain A drains while the wg computes chain B
// (and vice versa) -> latency leaves the critical path (r4/r8/r10 all
// converged to ~4ms = ~2us/step exposed latency; this hides it under the
// other chain's ~1us of compute).
//   - 8 sync domains of 64 wgs; poll = 64 flags, ONE flag per lane.
//   - gates/store/flag for A by wave 6, for B by wave 7; wave 0 polls ->
//     the store-ack RT never sits on the polling wave.
//   - each gate-wave defers vmcnt(0)+flag until after the NEXT x-proj, so
//     the h-store ack drains under compute.
//   - flag protocol + plain cached h reads = r8 (proven incl. replays).
// ---------------------------------------------------------------------------
__global__ __launch_bounds__(512, 1)
void lstm_kernel(const int* __restrict__ instr, const float* __restrict__ emb,
                 const float* __restrict__ wih_f, const float* __restrict__ whh_f,
                 const float* __restrict__ bih_f, const float* __restrict__ bhh_f,
                 const float* __restrict__ wih_b, const float* __restrict__ whh_b,
                 const float* __restrict__ bih_b, const float* __restrict__ bhh_b,
                 float* __restrict__ ws)
{
    float* h_hist = ws + OFF_HH;
    int* flags = (int*)ws;            // [2][4][64]

    const int wg     = blockIdx.x;    // 0..255
    const int bgrp   = wg & 3;        // batches bgrp*4..+3
    const int uslice = wg >> 2;       // 0..63
    const int U      = uslice * 8;    // 8 hidden units per wg per chain
    const int b0     = bgrp * 4;

    int* barfA = flags + (0*4 + bgrp)*64;
    int* barfB = flags + (1*4 + bgrp)*64;

    const int tid  = threadIdx.x;
    const int wid  = tid >> 6;        // 0..7
    const int lane = tid & 63;        // k-chunk id (8 k's per lane)

    // Weight slices: 4 rows per thread per chain (32 gate-rows = 4 gates x 8 units)
    // row r = wid*4+ri: gate = r>>3, ul = r&7; k = lane*8..+8
    float wiA[32], whA[32], wiB[32], whB[32];
#pragma unroll
    for (int ri = 0; ri < 4; ++ri){
        int r = wid*4 + ri;
        int gate = r >> 3, ul = r & 7;
        size_t row = (size_t)(gate*HD + U + ul) * HD + lane*8;
        float4 a0 = *(const float4*)(wih_f + row);
        float4 a1 = *(const float4*)(wih_f + row + 4);
        wiA[ri*8+0]=a0.x; wiA[ri*8+1]=a0.y; wiA[ri*8+2]=a0.z; wiA[ri*8+3]=a0.w;
        wiA[ri*8+4]=a1.x; wiA[ri*8+5]=a1.y; wiA[ri*8+6]=a1.z; wiA[ri*8+7]=a1.w;
        float4 b0v = *(const float4*)(whh_f + row);
        float4 b1v = *(const float4*)(whh_f + row + 4);
        whA[ri*8+0]=b0v.x; whA[ri*8+1]=b0v.y; whA[ri*8+2]=b0v.z; whA[ri*8+3]=b0v.w;
        whA[ri*8+4]=b1v.x; whA[ri*8+5]=b1v.y; whA[ri*8+6]=b1v.z; whA[ri*8+7]=b1v.w;
        float4 c0 = *(const float4*)(wih_b + row);
        float4 c1 = *(const float4*)(wih_b + row + 4);
        wiB[ri*8+0]=c0.x; wiB[ri*8+1]=c0.y; wiB[ri*8+2]=c0.z; wiB[ri*8+3]=c0.w;
        wiB[ri*8+4]=c1.x; wiB[ri*8+5]=c1.y; wiB[ri*8+6]=c1.z; wiB[ri*8+7]=c1.w;
        float4 d0 = *(const float4*)(whh_b + row);
        float4 d1 = *(const float4*)(whh_b + row + 4);
        whB[ri*8+0]=d0.x; whB[ri*8+1]=d0.y; whB[ri*8+2]=d0.z; whB[ri*8+3]=d0.w;
        whB[ri*8+4]=d1.x; whB[ri*8+5]=d1.y; whB[ri*8+6]=d1.z; whB[ri*8+7]=d1.w;
    }

    // Gate-wave biases: wave 6 -> chain A (fwd), wave 7 -> chain B (bwd).
    // lane t (<32) owns (b = b0 + (t>>3), unit = U + (t&7)).
    const float* bihX = (wid == 7) ? bih_b : bih_f;
    const float* bhhX = (wid == 7) ? bhh_b : bhh_f;
    const int ug = U + (lane & 7);
    const float bI = bihX[0*HD + ug] + bhhX[0*HD + ug];
    const float bF = bihX[1*HD + ug] + bhhX[1*HD + ug];
    const float bG = bihX[2*HD + ug] + bhhX[2*HD + ug];
    const float bO = bihX[3*HD + ug] + bhhX[3*HD + ug];
    float cst = 0.0f;

    __shared__ float gbuf[128];       // [gate][bi*8 + ul]

    // reduce-scatter ownership (16 values: 4 xor stages + 2 folds):
    // lane<16 ends holding full sum of j = bitrev4(lane&15); j = bi*4 + ri
    const int jown = ((lane&1)<<3)|((lane&2)<<1)|((lane&4)>>1)|((lane&8)>>3);
    const int own_bi  = jown >> 2;
    const int own_row = wid*4 + (jown & 3);
    const int gslot   = (own_row >> 3)*32 + own_bi*8 + (own_row & 7);

    // Prologue: gather xA for s=0 (tpA = 0)
    float4 xA[8], xB[8];
#pragma unroll
    for (int bi = 0; bi < 4; ++bi){
        int idx = instr[(b0+bi)*T + 0];
        const float* px = emb + (size_t)idx*HD + lane*8;
        xA[bi*2]   = *(const float4*)px;
        xA[bi*2+1] = *(const float4*)(px + 4);
    }

    for (int s = 0; s < T; ++s){
        const int tpA = s;
        const int tpB = T-1-s;
        float a[16];

        // ======== chain A (fwd) ========
#pragma unroll
        for (int j = 0; j < 16; ++j) a[j] = 0.0f;
#pragma unroll
        for (int bi = 0; bi < 4; ++bi){
            float xs[8] = {xA[bi*2].x,xA[bi*2].y,xA[bi*2].z,xA[bi*2].w,
                           xA[bi*2+1].x,xA[bi*2+1].y,xA[bi*2+1].z,xA[bi*2+1].w};
#pragma unroll
            for (int kk = 0; kk < 8; ++kk){
                float xv = xs[kk];
#pragma unroll
                for (int ri = 0; ri < 4; ++ri)
                    a[bi*4+ri] = fmaf(xv, wiA[ri*8+kk], a[bi*4+ri]);
            }
        }

        // wave7: post chain-B flag for step s-1 (h-stores drained; xA already waited)
        if (s > 0 && wid == 7){
            asm volatile("s_waitcnt vmcnt(0)" ::: "memory");
            __builtin_amdgcn_sched_barrier(0);
            if (lane == 0)
                __hip_atomic_store(barfB + uslice, s, __ATOMIC_RELAXED, __HIP_MEMORY_SCOPE_AGENT);
        }

        // gather xB for this step (consumed ~0.5us later; latency hidden)
#pragma unroll
        for (int bi = 0; bi < 4; ++bi){
            int idx = instr[(b0+bi)*T + tpB];
            const float* px = emb + (size_t)idx*HD + lane*8;
            xB[bi*2]   = *(const float4*)px;
            xB[bi*2+1] = *(const float4*)(px + 4);
        }

        // poll chain-A flags (wave0; 1 flag per lane)
        if (s > 0 && wid == 0){
            for (;;){
                int v = __hip_atomic_load(barfA + lane, __ATOMIC_RELAXED, __HIP_MEMORY_SCOPE_AGENT);
                if (__all(v >= s)) break;
                __builtin_amdgcn_s_sleep(1);
            }
        }
        __syncthreads();

        if (s > 0){
            const float* hbase = h_hist + (size_t)(s-1)*NB*HD;   // dir0, t = s-1
#pragma unroll
            for (int bi = 0; bi < 4; ++bi){
                const float* ph = hbase + (size_t)(b0+bi)*HD + lane*8;
                float4 h0 = *(const float4*)ph;
                float4 h1 = *(const float4*)(ph + 4);
                float hs[8] = {h0.x,h0.y,h0.z,h0.w,h1.x,h1.y,h1.z,h1.w};
#pragma unroll
                for (int kk = 0; kk < 8; ++kk){
                    float hv = hs[kk];
#pragma unroll
                    for (int ri = 0; ri < 4; ++ri)
                        a[bi*4+ri] = fmaf(hv, whA[ri*8+kk], a[bi*4+ri]);
                }
            }
        }

        // reduce-scatter 16 over 64 lanes
#pragma unroll
        for (int m = 0; m < 4; ++m){
            const int half = 8 >> m;
            const bool up = (lane >> m) & 1;
#pragma unroll
            for (int j = 0; j < 8; ++j){
                if (j < half){
                    float lo = a[j], hi = a[j+half];
                    float rlo = __shfl_xor(lo, 1<<m, 64);
                    float rhi = __shfl_xor(hi, 1<<m, 64);
                    a[j] = up ? (hi + rhi) : (lo + rlo);
                }
            }
        }
        a[0] += __shfl_xor(a[0], 16, 64);
        a[0] += __shfl_xor(a[0], 32, 64);
        if (lane < 16) gbuf[gslot] = a[0];
        __syncthreads();

        // gates A (wave 6)
        if (wid == 6){
            if (lane < 32){
                float iv = sigmoidf_(gbuf[      lane] + bI);
                float fv = sigmoidf_(gbuf[ 32 + lane] + bF);
                float gv = tanhf_  (gbuf[ 64 + lane] + bG);
                float ov = sigmoidf_(gbuf[ 96 + lane] + bO);
                cst = fv*cst + iv*gv;
                float hv = ov * tanhf_(cst);
                int b = b0 + (lane >> 3), ul = lane & 7;
                __hip_atomic_store(&h_hist[((size_t)tpA*NB + b)*HD + U + ul], hv,
                                   __ATOMIC_RELAXED, __HIP_MEMORY_SCOPE_AGENT);
            }
        }

        // ======== chain B (bwd) ========
#pragma unroll
        for (int j = 0; j < 16; ++j) a[j] = 0.0f;
#pragma unroll
        for (int bi = 0; bi < 4; ++bi){
            float xs[8] = {xB[bi*2].x,xB[bi*2].y,xB[bi*2].z,xB[bi*2].w,
                           xB[bi*2+1].x,xB[bi*2+1].y,xB[bi*2+1].z,xB[bi*2+1].w};
#pragma unroll
            for (int kk = 0; kk < 8; ++kk){
                float xv = xs[kk];
#pragma unroll
                for (int ri = 0; ri < 4; ++ri)
                    a[bi*4+ri] = fmaf(xv, wiB[ri*8+kk], a[bi*4+ri]);
            }
        }

        // wave6: A's h-stores drained under xprojB -> post chain-A flag
        if (wid == 6){
            asm volatile("s_waitcnt vmcnt(0)" ::: "memory");
            __builtin_amdgcn_sched_barrier(0);
            if (lane == 0)
                __hip_atomic_store(barfA + uslice, s + 1, __ATOMIC_RELAXED, __HIP_MEMORY_SCOPE_AGENT);
        }

        // poll chain-B flags (wave0)
        if (s > 0 && wid == 0){
            for (;;){
                int v = __hip_atomic_load(barfB + lane, __ATOMIC_RELAXED, __HIP_MEMORY_SCOPE_AGENT);
                if (__all(v >= s)) break;
                __builtin_amdgcn_s_sleep(1);
            }
        }
        __syncthreads();

        // gather xA for step s+1 (flies across the iteration boundary)
        if (s + 1 < T){
#pragma unroll
            for (int bi = 0; bi < 4; ++bi){
                int idx = instr[(b0+bi)*T + (s+1)];
                const float* px = emb + (size_t)idx*HD + lane*8;
                xA[bi*2]   = *(const float4*)px;
                xA[bi*2+1] = *(const float4*)(px + 4);
            }
        }

        if (s > 0){
            const float* hbase = h_hist + (size_t)(T + (T - s))*NB*HD;  // dir1, t = T-s
#pragma unroll
            for (int bi = 0; bi < 4; ++bi){
                const float* ph = hbase + (size_t)(b0+bi)*HD + lane*8;
                float4 h0 = *(const float4*)ph;
                float4 h1 = *(const float4*)(ph + 4);
                float hs[8] = {h0.x,h0.y,h0.z,h0.w,h1.x,h1.y,h1.z,h1.w};
#pragma unroll
                for (int kk = 0; kk < 8; ++kk){
                    float hv = hs[kk];
#pragma unroll
                    for (int ri = 0; ri < 4; ++ri)
                        a[bi*4+ri] = fmaf(hv, whB[ri*8+kk], a[bi*4+ri]);
                }
            }
        }

#pragma unroll
        for (int m = 0; m < 4; ++m){
            const int half = 8 >> m;
            const bool up = (lane >> m) & 1;
#pragma unroll
            for (int j = 0; j < 8; ++j){
                if (j < half){
                    float lo = a[j], hi = a[j+half];
                    float rlo = __shfl_xor(lo, 1<<m, 64);
                    float rhi = __shfl_xor(hi, 1<<m, 64);
                    a[j] = up ? (hi + rhi) : (lo + rlo);
                }
            }
        }
        a[0] += __shfl_xor(a[0], 16, 64);
        a[0] += __shfl_xor(a[0], 32, 64);
        if (lane < 16) gbuf[gslot] = a[0];
        __syncthreads();

        // gates B (wave 7); flag posted at the TOP of the next iteration
        if (wid == 7){
            if (lane < 32){
                float iv = sigmoidf_(gbuf[      lane] + bI);
                float fv = sigmoidf_(gbuf[ 32 + lane] + bF);
                float gv = tanhf_  (gbuf[ 64 + lane] + bG);
                float ov = sigmoidf_(gbuf[ 96 + lane] + bO);
                cst = fv*cst + iv*gv;
                float hv = ov * tanhf_(cst);
                int b = b0 + (lane >> 3), ul = lane & 7;
                __hip_atomic_store(&h_hist[((size_t)(T + tpB)*NB + b)*HD + U + ul], hv,
                                   __ATOMIC_RELAXED, __HIP_MEMORY_SCOPE_AGENT);
            }
        }
    }
}

// ---------------------------------------------------------------------------
// SH = relu(enc @ ws1.T + bs1)   M=16384 N=512 K=1024, fp32 64x64x16 tiles
// ---------------------------------------------------------------------------
__global__ __launch_bounds__(256, 2)
void seg_gemm(const float* __restrict__ ws_, const float* __restrict__ ws1,
              const float* __restrict__ bs1)
{
    const float* h_hist = ws_ + OFF_HH;
    float* SH = (float*)(ws_ + OFF_SH);
    __shared__ float As[64][17];
    __shared__ float Bs[64][17];
    const int m0 = blockIdx.x * 64;
    const int n0 = blockIdx.y * 64;
    const int tid = threadIdx.x;
    const int r  = tid >> 2;
    const int kq = (tid & 3) * 4;
    const int ty = tid >> 4, tx = tid & 15;
    const int bI = m0 >> 10;          // tile stays inside one batch
    const int t0 = m0 & 1023;

    float acc[4][4];
#pragma unroll
    for (int i=0;i<4;i++)
#pragma unroll
        for (int j=0;j<4;j++) acc[i][j]=0.0f;

    for (int kb = 0; kb < 1024; kb += 16){
        int kk = kb + kq;
        const float* ap = (kk < 512)
            ? h_hist + ((size_t)(t0 + r)*NB + bI)*HD + kk
            : h_hist + ((size_t)(T + t0 + r)*NB + bI)*HD + (kk - 512);
        float4 av = *(const float4*)ap;
        As[r][kq+0]=av.x; As[r][kq+1]=av.y; As[r][kq+2]=av.z; As[r][kq+3]=av.w;
        float4 bv = *(const float4*)(ws1 + (size_t)(n0 + r)*1024 + kk);
        Bs[r][kq+0]=bv.x; Bs[r][kq+1]=bv.y; Bs[r][kq+2]=bv.z; Bs[r][kq+3]=bv.w;
        __syncthreads();
#pragma unroll
        for (int k2 = 0; k2 < 16; ++k2){
            float av_[4], bv_[4];
#pragma unroll
            for (int i=0;i<4;i++) av_[i] = As[ty*4+i][k2];
#pragma unroll
            for (int j=0;j<4;j++) bv_[j] = Bs[tx*4+j][k2];
#pragma unroll
            for (int i=0;i<4;i++)
#pragma unroll
                for (int j=0;j<4;j++) acc[i][j] = fmaf(av_[i], bv_[j], acc[i][j]);
        }
        __syncthreads();
    }
#pragma unroll
    for (int i=0;i<4;i++){
        int m = m0 + ty*4 + i;
#pragma unroll
        for (int j=0;j<4;j++){
            int n = n0 + tx*4 + j;
            SH[(size_t)m*512 + n] = fmaxf(acc[i][j] + bs1[n], 0.0f);
        }
    }
}

// ---------------------------------------------------------------------------
// scores -> sigmoid -> seg_probs (ws copy + d_out)
// ---------------------------------------------------------------------------
__global__ void seg_score(const float* __restrict__ ws_, const float* __restrict__ ws2,
                          const float* __restrict__ bs2, float* __restrict__ dout)
{
    const float* SH = ws_ + OFF_SH;
    float* segp = (float*)(ws_ + OFF_SEGP);
    int row  = blockIdx.x*4 + (threadIdx.x >> 6);
    int lane = threadIdx.x & 63;
    const float* p = SH + (size_t)row*512 + lane*8;
    const float* q = ws2 + lane*8;
    float4 a0=*(const float4*)p, a1=*(const float4*)(p+4);
    float4 b0=*(const float4*)q, b1=*(const float4*)(q+4);
    float ssum = a0.x*b0.x + a0.y*b0.y + a0.z*b0.z + a0.w*b0.w
               + a1.x*b1.x + a1.y*b1.y + a1.z*b1.z + a1.w*b1.w;
#pragma unroll
    for (int m=1;m<64;m<<=1) ssum += __shfl_xor(ssum, m, 64);
    if (lane == 0){
        float z = ssum + bs2[0];
        float pr = 1.0f/(1.0f + __expf(-z));
        segp[row] = pr;
        dout[81920 + row] = pr;
    }
}

// ---------------------------------------------------------------------------
// Per-batch: mask scan (count, first-10 idx), pooled -> gctx
// ---------------------------------------------------------------------------
__global__ void select_gctx(float* __restrict__ ws_, const float* __restrict__ wgm,
                            const float* __restrict__ bgv)
{
    const float* h_hist = ws_ + OFF_HH;
    const float* segp   = ws_ + OFF_SEGP;
    float* gctx = ws_ + OFF_GCTX;
    int* sel = (int*)(ws_ + OFF_SEL);
    int b = blockIdx.x, tid = threadIdx.x;
    __shared__ unsigned char flag[1024];
    __shared__ float pool[1024];
    for (int j = tid; j < 1024; j += 256){
        flag[j] = segp[b*1024 + j] > 0.5f ? 1 : 0;
        pool[j] = (j < 512) ? h_hist[((size_t)1023*NB + b)*HD + j]
                            : h_hist[((size_t)T*NB + b)*HD + (j - 512)];
    }
    __syncthreads();
    if (tid == 0){
        int c = 0;
        int tmp[10];
        for (int j = 0; j < 10; ++j) tmp[j] = 0;
        for (int t = 0; t < 1024; ++t){
            if (flag[t]){ if (c < 10) tmp[c] = t; c++; }
        }
        for (int j = 0; j < 10; ++j) sel[b*12 + j] = tmp[j];
        sel[b*12 + 10] = c;
        sel[b*12 + 11] = 0;
    }
    __syncthreads();
    for (int n = tid; n < 1024; n += 256){
        float acc = bgv[n];
        const float* wr = wgm + (size_t)n*1024;
        for (int k = 0; k < 1024; k += 4){
            acc += wr[k]*pool[k] + wr[k+1]*pool[k+1] + wr[k+2]*pool[k+2] + wr[k+3]*pool[k+3];
        }
        gctx[b*1024 + n] = acc;
    }
}

// ---------------------------------------------------------------------------
// Decoder: one block per (b,slot)
// ---------------------------------------------------------------------------
__global__ void decode(const float* __restrict__ ws_, const float* __restrict__ wd1,
                       const float* __restrict__ bd1, const float* __restrict__ wd2,
                       const float* __restrict__ bd2, float* __restrict__ dout)
{
    const float* h_hist = ws_ + OFF_HH;
    const float* gctx   = ws_ + OFF_GCTX;
    const int* sel = (const int*)(ws_ + OFF_SEL);
    int blk = blockIdx.x;
    int b = blk / 10, slot = blk % 10;
    int tid = threadIdx.x;
    int count = sel[b*12 + 10];
    int nval = count < 10 ? count : 10;
    bool empty = (count == 0);
    float* outp = dout + (size_t)(b*10 + slot)*512;
    if (slot >= nval && !(empty && slot == 0)){
        for (int n = tid; n < 512; n += 256) outp[n] = 0.0f;
        return;
    }
    __shared__ float row[1024];
    __shared__ float dh[512];
    if (empty){
        for (int j = tid; j < 1024; j += 256) row[j] = gctx[b*1024 + j];
    } else {
        int t = sel[b*12 + slot];
        for (int j = tid; j < 1024; j += 256)
            row[j] = (j < 512) ? h_hist[((size_t)t*NB + b)*HD + j]
                               : h_hist[((size_t)(T + t)*NB + b)*HD + (j-512)];
    }
    __syncthreads();
    for (int d = tid; d < 512; d += 256){
        float acc = bd1[d];
        const float* wr = wd1 + (size_t)d*1024;
        for (int k = 0; k < 1024; ++k) acc += wr[k]*row[k];
        dh[d] = fmaxf(acc, 0.0f);
    }
    __syncthreads();
    for (int n = tid; n < 512; n += 256){
        float acc = bd2[n];
        const float* wr = wd2 + (size_t)n*512;
        for (int k = 0; k < 512; ++k) acc += wr[k]*dh[k];
        outp[n] = acc;
    }
}

extern "C" void kernel_launch(void* const* d_in, const int* in_sizes, int n_in,
                              void* d_out, int out_size, void* d_ws, size_t ws_size,
                              hipStream_t stream)
{
    const int*   instr = (const int*)d_in[0];
    const float* emb   = (const float*)d_in[1];
    const float* wih_f = (const float*)d_in[2];
    const float* whh_f = (const float*)d_in[3];
    const float* bih_f = (const float*)d_in[4];
    const float* bhh_f = (const float*)d_in[5];
    const float* wih_b = (const float*)d_in[6];
    const float* whh_b = (const float*)d_in[7];
    const float* bih_b = (const float*)d_in[8];
    const float* bhh_b = (const float*)d_in[9];
    const float* wg_   = (const float*)d_in[10];
    const float* bg_   = (const float*)d_in[11];
    const float* ws1   = (const float*)d_in[12];
    const float* bs1   = (const float*)d_in[13];
    const float* ws2   = (const float*)d_in[14];
    const float* bs2   = (const float*)d_in[15];
    const float* wd1   = (const float*)d_in[16];
    const float* bd1   = (const float*)d_in[17];
    const float* wd2   = (const float*)d_in[18];
    const float* bd2   = (const float*)d_in[19];
    float* out = (float*)d_out;
    float* ws  = (float*)d_ws;

    // zero the per-wg step flags (captured as a memset node; re-runs every replay)
    hipMemsetAsync(d_ws, 0, 2048, stream);

    hipLaunchKernelGGL(lstm_kernel, dim3(256), dim3(512), 0, stream,
                       instr, emb, wih_f, whh_f, bih_f, bhh_f,
                       wih_b, whh_b, bih_b, bhh_b, ws);
    hipLaunchKernelGGL(seg_gemm, dim3(256, 8), dim3(256), 0, stream, ws, ws1, bs1);
    hipLaunchKernelGGL(seg_score, dim3(4096), dim3(256), 0, stream, ws, ws2, bs2, out);
    hipLaunchKernelGGL(select_gctx, dim3(16), dim3(256), 0, stream, ws, wg_, bg_);
    hipLaunchKernelGGL(decode, dim3(160), dim3(256), 0, stream, ws, wd1, bd1, wd2, bd2, out);
}

// Round 12
// 4728.288 us; speedup vs baseline: 1.3459x; 1.3459x over previous
//
#include <hip/hip_runtime.h>
#include <math.h>

// Problem constants (fixed by reference)
#define T   1024
#define NB  16
#define HD  512

// ws layout (float offsets)
#define OFF_BAR  0                         // 256 ints: flag[2 dir][4 bgrp][32 uslice]
#define OFF_HH   256                       // h_hist [2][T][NB][HD] = 16,777,216 floats
#define OFF_SH   (OFF_HH + 16777216)       // SH [16384][512] = 8,388,608 floats
#define OFF_SEGP (OFF_SH + 8388608)        // [16384]
#define OFF_GCTX (OFF_SEGP + 16384)        // [16][1024]
#define OFF_SEL  (OFF_GCTX + 16384)        // ints [16][12]

typedef unsigned long long u64;

__device__ __forceinline__ float sigmoidf_(float x){ return 1.0f/(1.0f + __expf(-x)); }
// fast tanh via exp2-based __expf; |err| ~1e-7, graceful saturation at +/-1
__device__ __forceinline__ float tanhf_(float x){ return 1.0f - 2.0f/(1.0f + __expf(2.0f*x)); }

__device__ __forceinline__ bool clean8(const float4* hq){
    unsigned ok = 1u;
#pragma unroll
    for (int q = 0; q < 8; ++q){
        ok &= (__float_as_uint(hq[q].x) != 0xFFFFFFFFu) ? 1u : 0u;
        ok &= (__float_as_uint(hq[q].y) != 0xFFFFFFFFu) ? 1u : 0u;
        ok &= (__float_as_uint(hq[q].z) != 0xFFFFFFFFu) ? 1u : 0u;
        ok &= (__float_as_uint(hq[q].w) != 0xFFFFFFFFu) ? 1u : 0u;
    }
    return ok != 0u;
}

// ---------------------------------------------------------------------------
// Persistent bidirectional LSTM. grid=256 wgs (1 per CU), block=512 (8 waves).
// Partition (r8/r10, proven): wg -> (dir = wg&1, bgrp = (wg>>1)&3 : 4 batches,
// uslice = wg>>3 : 16 units). 8 independent sync domains of 32 wgs.
//
// Sync = HYBRID flags-without-ack + canary-verified data (r12):
//   - h_hist canary-armed (0xFF = -NaN, unreachable by h=o*tanh(c)) per call.
//   - producer wave0: sc1 h-stores, then lane0 posts flag IMMEDIATELY (NO
//     vmcnt ack -- in-order issue guarantees stores issued before the flag;
//     ARRIVAL order is covered by the canary check on the data).
//   - consumer wave0: polls 32 flags (1/lane, ~0.15us body -- vs r10's
//     1024-transaction data-poll ~0.8us body), then reads h via plain cached
//     float4 (fresh address per step -> first touch -> LLC; r8-proven),
//     canary-verifies, rare-race fallback = r10 atomic u64 reload loop (sc1,
//     immune to a stale-canary L2 line).
//   - wave0 relays h to LDS hxch; siblings read LDS (r10, proven).
// ---------------------------------------------------------------------------
__global__ __launch_bounds__(512, 1)
void lstm_kernel(const int* __restrict__ instr, const float* __restrict__ emb,
                 const float* __restrict__ wih_f, const float* __restrict__ whh_f,
                 const float* __restrict__ bih_f, const float* __restrict__ bhh_f,
                 const float* __restrict__ wih_b, const float* __restrict__ whh_b,
                 const float* __restrict__ bih_b, const float* __restrict__ bhh_b,
                 float* __restrict__ ws)
{
    float* h_hist = ws + OFF_HH;
    int* flags = (int*)ws;            // [2][4][32]

    const int wg     = blockIdx.x;    // 0..255
    const int dir    = wg & 1;
    const int bgrp   = (wg >> 1) & 3; // batch group: batches bgrp*4..+3
    const int uslice = wg >> 3;       // 0..31
    const int U      = uslice * 16;   // hidden-unit base (16 units per wg)
    const int b0     = bgrp * 4;

    int* barf = flags + (dir*4 + bgrp)*32;

    const float* wih = dir ? wih_b : wih_f;
    const float* whh = dir ? whh_b : whh_f;
    const float* bih = dir ? bih_b : bih_f;
    const float* bhh = dir ? bhh_b : bhh_f;

    const int tid  = threadIdx.x;
    const int wid  = tid >> 6;        // 0..7 = row-group
    const int lane = tid & 63;        // k-chunk id (8 k's per lane)
    const int rg   = wid;             // rows rg*8 .. rg*8+7 of the wg's 64

    // Load weight slices into registers: row rgl = rg*8+ri of 64
    // (gate = rgl>>4, local unit = rgl&15), k = lane*8..+8
    float wi[64], wh[64];
#pragma unroll
    for (int ri = 0; ri < 8; ++ri){
        int rgl = rg*8 + ri;
        int gate = rgl >> 4, ul = rgl & 15;
        size_t row = (size_t)(gate*HD + U + ul) * HD + lane*8;
        float4 a0 = *(const float4*)(wih + row);
        float4 a1 = *(const float4*)(wih + row + 4);
        float4 b0v = *(const float4*)(whh + row);
        float4 b1v = *(const float4*)(whh + row + 4);
        wi[ri*8+0]=a0.x; wi[ri*8+1]=a0.y; wi[ri*8+2]=a0.z; wi[ri*8+3]=a0.w;
        wi[ri*8+4]=a1.x; wi[ri*8+5]=a1.y; wi[ri*8+6]=a1.z; wi[ri*8+7]=a1.w;
        wh[ri*8+0]=b0v.x; wh[ri*8+1]=b0v.y; wh[ri*8+2]=b0v.z; wh[ri*8+3]=b0v.w;
        wh[ri*8+4]=b1v.x; wh[ri*8+5]=b1v.y; wh[ri*8+6]=b1v.z; wh[ri*8+7]=b1v.w;
    }

    // Biases for owner lanes: wave0 lane M owns (b = b0 + (M>>4), unit = U + (M&15))
    float bI, bF, bG, bO, cst = 0.0f;
    {
        int u = tid & 15;
        bI = bih[0*HD + U + u] + bhh[0*HD + U + u];
        bF = bih[1*HD + U + u] + bhh[1*HD + U + u];
        bG = bih[2*HD + U + u] + bhh[2*HD + U + u];
        bO = bih[3*HD + U + u] + bhh[3*HD + U + u];
    }

    __shared__ float hxch[8*4*64];    // [q][bi][lane]: h value k=lane*8+q, batch b0+bi
    __shared__ float gbuf[256];       // [gate][b_local*16 + ulocal]

    // reduce-scatter ownership (32 values, 5 xor stages + cross-half merge):
    const int jown = ((lane&1)<<4)|((lane&2)<<2)|(lane&4)|((lane&8)>>2)|((lane&16)>>4);
    const int own_bi  = jown >> 3;            // 0..3
    const int own_rgl = rg*8 + (jown & 7);    // 0..63
    const int gslot   = (own_rgl >> 4)*64 + own_bi*16 + (own_rgl & 15);

    for (int s = 0; s < T; ++s){
        const int tp = dir ? (T-1-s) : s;   // original-time index

        // ---- x gather + x-projection: independent of the recurrence
        float a[32];
#pragma unroll
        for (int j = 0; j < 32; ++j) a[j] = 0.0f;

#pragma unroll
        for (int bi = 0; bi < 4; ++bi){
            int b = b0 + bi;
            int idx = instr[b*T + tp];
            const float* px = emb + (size_t)idx*HD + lane*8;
            float4 x0 = *(const float4*)px;
            float4 x1 = *(const float4*)(px + 4);
            float xs[8] = {x0.x,x0.y,x0.z,x0.w,x1.x,x1.y,x1.z,x1.w};
#pragma unroll
            for (int kk = 0; kk < 8; ++kk){
                float xv = xs[kk];
#pragma unroll
                for (int ri = 0; ri < 8; ++ri)
                    a[bi*8+ri] = fmaf(xv, wi[ri*8+kk], a[bi*8+ri]);
            }
        }

        if (s > 0){
            const int tprev = dir ? (T - s) : (s - 1);
            const float* hbase = h_hist + (size_t)(dir*T + tprev)*NB*HD;

            if (wid == 0){
                // ---- cheap flag poll (1 flag per lane; ~0.15us body)
                for (;;){
                    int v = (lane < 32)
                        ? __hip_atomic_load(barf + lane, __ATOMIC_RELAXED, __HIP_MEMORY_SCOPE_AGENT)
                        : 0x7fffffff;
                    if (__all(v >= s)) break;
                    __builtin_amdgcn_s_sleep(1);
                }
                // ---- first-touch plain loads (fresh addr -> L2 miss -> LLC)
                float4 hq[8];
#pragma unroll
                for (int bi = 0; bi < 4; ++bi){
                    const float* ph = hbase + (size_t)(b0+bi)*HD + lane*8;
                    hq[bi*2]   = *(const float4*)ph;
                    hq[bi*2+1] = *(const float4*)(ph + 4);
                }
                // ---- canary verify; rare-race fallback via sc1 atomic loads
                while (!__all(clean8(hq))){
#pragma unroll
                    for (int bi = 0; bi < 4; ++bi){
                        const u64* p = (const u64*)(hbase + (size_t)(b0+bi)*HD + lane*8);
                        u64 q0 = __hip_atomic_load(p+0, __ATOMIC_RELAXED, __HIP_MEMORY_SCOPE_AGENT);
                        u64 q1 = __hip_atomic_load(p+1, __ATOMIC_RELAXED, __HIP_MEMORY_SCOPE_AGENT);
                        u64 q2 = __hip_atomic_load(p+2, __ATOMIC_RELAXED, __HIP_MEMORY_SCOPE_AGENT);
                        u64 q3 = __hip_atomic_load(p+3, __ATOMIC_RELAXED, __HIP_MEMORY_SCOPE_AGENT);
                        float2 f0 = __builtin_bit_cast(float2, q0);
                        float2 f1 = __builtin_bit_cast(float2, q1);
                        float2 f2 = __builtin_bit_cast(float2, q2);
                        float2 f3 = __builtin_bit_cast(float2, q3);
                        hq[bi*2]   = make_float4(f0.x, f0.y, f1.x, f1.y);
                        hq[bi*2+1] = make_float4(f2.x, f2.y, f3.x, f3.y);
                    }
                }
                // ---- relay to LDS (stride-4B across lanes: conflict-free)
#pragma unroll
                for (int bi = 0; bi < 4; ++bi){
                    hxch[0*256 + bi*64 + lane] = hq[bi*2].x;
                    hxch[1*256 + bi*64 + lane] = hq[bi*2].y;
                    hxch[2*256 + bi*64 + lane] = hq[bi*2].z;
                    hxch[3*256 + bi*64 + lane] = hq[bi*2].w;
                    hxch[4*256 + bi*64 + lane] = hq[bi*2+1].x;
                    hxch[5*256 + bi*64 + lane] = hq[bi*2+1].y;
                    hxch[6*256 + bi*64 + lane] = hq[bi*2+1].z;
                    hxch[7*256 + bi*64 + lane] = hq[bi*2+1].w;
                }
            }
            __syncthreads();   // releases waves 1..7; hxch visible

            // ---- h-projection from LDS (all waves; no global RT)
#pragma unroll
            for (int bi = 0; bi < 4; ++bi){
                float hs[8];
#pragma unroll
                for (int kk = 0; kk < 8; ++kk)
                    hs[kk] = hxch[kk*256 + bi*64 + lane];
#pragma unroll
                for (int kk = 0; kk < 8; ++kk){
                    float hv = hs[kk];
#pragma unroll
                    for (int ri = 0; ri < 8; ++ri)
                        a[bi*8+ri] = fmaf(hv, wh[ri*8+kk], a[bi*8+ri]);
                }
            }
        }

        // ---- reduce-scatter: 32 values over 64 lanes (5 stages + merge)
#pragma unroll
        for (int m = 0; m < 5; ++m){
            const int half = 16 >> m;
            const bool up = (lane >> m) & 1;
#pragma unroll
            for (int j = 0; j < 16; ++j){
                if (j < half){
                    float lo = a[j], hi = a[j+half];
                    float rlo = __shfl_xor(lo, 1<<m, 64);
                    float rhi = __shfl_xor(hi, 1<<m, 64);
                    a[j] = up ? (hi + rhi) : (lo + rlo);
                }
            }
        }
        a[0] += __shfl_xor(a[0], 32, 64);   // cross-half k merge

        if ((lane & 32) == 0) gbuf[gslot] = a[0];
        __syncthreads();

        if (tid < 64){   // wave-uniform branch: wave0 only
            float iv = sigmoidf_(gbuf[      tid] + bI);
            float fv = sigmoidf_(gbuf[ 64 + tid] + bF);
            float gv = tanhf_  (gbuf[128 + tid] + bG);
            float ov = sigmoidf_(gbuf[192 + tid] + bO);
            cst = fv*cst + iv*gv;
            float hv = ov * tanhf_(cst);
            int b = b0 + (tid >> 4), u = tid & 15;
            // sc1 store, fire-and-forget: canary on data covers arrival order
            __hip_atomic_store(&h_hist[((size_t)(dir*T + tp)*NB + b)*HD + U + u], hv,
                               __ATOMIC_RELAXED, __HIP_MEMORY_SCOPE_AGENT);
        }
        // flag posted immediately -- NO vmcnt ack (issue order is program
        // order within wave0; data-arrival races are caught by the canary)
        if (tid == 0)
            __hip_atomic_store(barf + uslice, s + 1, __ATOMIC_RELAXED, __HIP_MEMORY_SCOPE_AGENT);
        // WAR safety: identical to r10 (hxch rewritten only after next poll,
        // gbuf(s+1) written only after post-poll barrier which wave0 reaches
        // after its gbuf reads here).
    }
}

// ---------------------------------------------------------------------------
// SH = relu(enc @ ws1.T + bs1)   M=16384 N=512 K=1024, fp32 64x64x16 tiles
// ---------------------------------------------------------------------------
__global__ __launch_bounds__(256, 2)
void seg_gemm(const float* __restrict__ ws_, const float* __restrict__ ws1,
              const float* __restrict__ bs1)
{
    const float* h_hist = ws_ + OFF_HH;
    float* SH = (float*)(ws_ + OFF_SH);
    __shared__ float As[64][17];
    __shared__ float Bs[64][17];
    const int m0 = blockIdx.x * 64;
    const int n0 = blockIdx.y * 64;
    const int tid = threadIdx.x;
    const int r  = tid >> 2;
    const int kq = (tid & 3) * 4;
    const int ty = tid >> 4, tx = tid & 15;
    const int bI = m0 >> 10;          // tile stays inside one batch
    const int t0 = m0 & 1023;

    float acc[4][4];
#pragma unroll
    for (int i=0;i<4;i++)
#pragma unroll
        for (int j=0;j<4;j++) acc[i][j]=0.0f;

    for (int kb = 0; kb < 1024; kb += 16){
        int kk = kb + kq;
        const float* ap = (kk < 512)
            ? h_hist + ((size_t)(t0 + r)*NB + bI)*HD + kk
            : h_hist + ((size_t)(T + t0 + r)*NB + bI)*HD + (kk - 512);
        float4 av = *(const float4*)ap;
        As[r][kq+0]=av.x; As[r][kq+1]=av.y; As[r][kq+2]=av.z; As[r][kq+3]=av.w;
        float4 bv = *(const float4*)(ws1 + (size_t)(n0 + r)*1024 + kk);
        Bs[r][kq+0]=bv.x; Bs[r][kq+1]=bv.y; Bs[r][kq+2]=bv.z; Bs[r][kq+3]=bv.w;
        __syncthreads();
#pragma unroll
        for (int k2 = 0; k2 < 16; ++k2){
            float av_[4], bv_[4];
#pragma unroll
            for (int i=0;i<4;i++) av_[i] = As[ty*4+i][k2];
#pragma unroll
            for (int j=0;j<4;j++) bv_[j] = Bs[tx*4+j][k2];
#pragma unroll
            for (int i=0;i<4;i++)
#pragma unroll
                for (int j=0;j<4;j++) acc[i][j] = fmaf(av_[i], bv_[j], acc[i][j]);
        }
        __syncthreads();
    }
#pragma unroll
    for (int i=0;i<4;i++){
        int m = m0 + ty*4 + i;
#pragma unroll
        for (int j=0;j<4;j++){
            int n = n0 + tx*4 + j;
            SH[(size_t)m*512 + n] = fmaxf(acc[i][j] + bs1[n], 0.0f);
        }
    }
}

// ---------------------------------------------------------------------------
// scores -> sigmoid -> seg_probs (ws copy + d_out)
// ---------------------------------------------------------------------------
__global__ void seg_score(const float* __restrict__ ws_, const float* __restrict__ ws2,
                          const float* __restrict__ bs2, float* __restrict__ dout)
{
    const float* SH = ws_ + OFF_SH;
    float* segp = (float*)(ws_ + OFF_SEGP);
    int row  = blockIdx.x*4 + (threadIdx.x >> 6);
    int lane = threadIdx.x & 63;
    const float* p = SH + (size_t)row*512 + lane*8;
    const float* q = ws2 + lane*8;
    float4 a0=*(const float4*)p, a1=*(const float4*)(p+4);
    float4 b0=*(const float4*)q, b1=*(const float4*)(q+4);
    float ssum = a0.x*b0.x + a0.y*b0.y + a0.z*b0.z + a0.w*b0.w
               + a1.x*b1.x + a1.y*b1.y + a1.z*b1.z + a1.w*b1.w;
#pragma unroll
    for (int m=1;m<64;m<<=1) ssum += __shfl_xor(ssum, m, 64);
    if (lane == 0){
        float z = ssum + bs2[0];
        float pr = 1.0f/(1.0f + __expf(-z));
        segp[row] = pr;
        dout[81920 + row] = pr;
    }
}

// ---------------------------------------------------------------------------
// Per-batch: mask scan (count, first-10 idx), pooled -> gctx
// ---------------------------------------------------------------------------
__global__ void select_gctx(float* __restrict__ ws_, const float* __restrict__ wgm,
                            const float* __restrict__ bgv)
{
    const float* h_hist = ws_ + OFF_HH;
    const float* segp   = ws_ + OFF_SEGP;
    float* gctx = ws_ + OFF_GCTX;
    int* sel = (int*)(ws_ + OFF_SEL);
    int b = blockIdx.x, tid = threadIdx.x;
    __shared__ unsigned char flag[1024];
    __shared__ float pool[1024];
    for (int j = tid; j < 1024; j += 256){
        flag[j] = segp[b*1024 + j] > 0.5f ? 1 : 0;
        pool[j] = (j < 512) ? h_hist[((size_t)1023*NB + b)*HD + j]
                            : h_hist[((size_t)T*NB + b)*HD + (j - 512)];
    }
    __syncthreads();
    if (tid == 0){
        int c = 0;
        int tmp[10];
        for (int j = 0; j < 10; ++j) tmp[j] = 0;
        for (int t = 0; t < 1024; ++t){
            if (flag[t]){ if (c < 10) tmp[c] = t; c++; }
        }
        for (int j = 0; j < 10; ++j) sel[b*12 + j] = tmp[j];
        sel[b*12 + 10] = c;
        sel[b*12 + 11] = 0;
    }
    __syncthreads();
    for (int n = tid; n < 1024; n += 256){
        float acc = bgv[n];
        const float* wr = wgm + (size_t)n*1024;
        for (int k = 0; k < 1024; k += 4){
            acc += wr[k]*pool[k] + wr[k+1]*pool[k+1] + wr[k+2]*pool[k+2] + wr[k+3]*pool[k+3];
        }
        gctx[b*1024 + n] = acc;
    }
}

// ---------------------------------------------------------------------------
// Decoder: one block per (b,slot)
// ---------------------------------------------------------------------------
__global__ void decode(const float* __restrict__ ws_, const float* __restrict__ wd1,
                       const float* __restrict__ bd1, const float* __restrict__ wd2,
                       const float* __restrict__ bd2, float* __restrict__ dout)
{
    const float* h_hist = ws_ + OFF_HH;
    const float* gctx   = ws_ + OFF_GCTX;
    const int* sel = (const int*)(ws_ + OFF_SEL);
    int blk = blockIdx.x;
    int b = blk / 10, slot = blk % 10;
    int tid = threadIdx.x;
    int count = sel[b*12 + 10];
    int nval = count < 10 ? count : 10;
    bool empty = (count == 0);
    float* outp = dout + (size_t)(b*10 + slot)*512;
    if (slot >= nval && !(empty && slot == 0)){
        for (int n = tid; n < 512; n += 256) outp[n] = 0.0f;
        return;
    }
    __shared__ float row[1024];
    __shared__ float dh[512];
    if (empty){
        for (int j = tid; j < 1024; j += 256) row[j] = gctx[b*1024 + j];
    } else {
        int t = sel[b*12 + slot];
        for (int j = tid; j < 1024; j += 256)
            row[j] = (j < 512) ? h_hist[((size_t)t*NB + b)*HD + j]
                               : h_hist[((size_t)(T + t)*NB + b)*HD + (j-512)];
    }
    __syncthreads();
    for (int d = tid; d < 512; d += 256){
        float acc = bd1[d];
        const float* wr = wd1 + (size_t)d*1024;
        for (int k = 0; k < 1024; ++k) acc += wr[k]*row[k];
        dh[d] = fmaxf(acc, 0.0f);
    }
    __syncthreads();
    for (int n = tid; n < 512; n += 256){
        float acc = bd2[n];
        const float* wr = wd2 + (size_t)n*512;
        for (int k = 0; k < 512; ++k) acc += wr[k]*dh[k];
        outp[n] = acc;
    }
}

extern "C" void kernel_launch(void* const* d_in, const int* in_sizes, int n_in,
                              void* d_out, int out_size, void* d_ws, size_t ws_size,
                              hipStream_t stream)
{
    const int*   instr = (const int*)d_in[0];
    const float* emb   = (const float*)d_in[1];
    const float* wih_f = (const float*)d_in[2];
    const float* whh_f = (const float*)d_in[3];
    const float* bih_f = (const float*)d_in[4];
    const float* bhh_f = (const float*)d_in[5];
    const float* wih_b = (const float*)d_in[6];
    const float* whh_b = (const float*)d_in[7];
    const float* bih_b = (const float*)d_in[8];
    const float* bhh_b = (const float*)d_in[9];
    const float* wg_   = (const float*)d_in[10];
    const float* bg_   = (const float*)d_in[11];
    const float* ws1   = (const float*)d_in[12];
    const float* bs1   = (const float*)d_in[13];
    const float* ws2   = (const float*)d_in[14];
    const float* bs2   = (const float*)d_in[15];
    const float* wd1   = (const float*)d_in[16];
    const float* bd1   = (const float*)d_in[17];
    const float* wd2   = (const float*)d_in[18];
    const float* bd2   = (const float*)d_in[19];
    float* out = (float*)d_out;
    float* ws  = (float*)d_ws;

    // zero the flags + canary-arm the h exchange buffer (re-arms every replay)
    hipMemsetAsync(d_ws, 0, 1024, stream);
    hipMemsetAsync((char*)d_ws + (size_t)OFF_HH*4, 0xFF, (size_t)16777216*4, stream);

    hipLaunchKernelGGL(lstm_kernel, dim3(256), dim3(512), 0, stream,
                       instr, emb, wih_f, whh_f, bih_f, bhh_f,
                       wih_b, whh_b, bih_b, bhh_b, ws);
    hipLaunchKernelGGL(seg_gemm, dim3(256, 8), dim3(256), 0, stream, ws, ws1, bs1);
    hipLaunchKernelGGL(seg_score, dim3(4096), dim3(256), 0, stream, ws, ws2, bs2, out);
    hipLaunchKernelGGL(select_gctx, dim3(16), dim3(256), 0, stream, ws, wg_, bg_);
    hipLaunchKernelGGL(decode, dim3(160), dim3(256), 0, stream, ws, wd1, bd1, wd2, bd2, out);
}